// Round 1
// baseline (544.947 us; speedup 1.0000x reference)
//
#include <hip/hip_runtime.h>
#include <math.h>

// Masked-mean BCE-with-logits:
//   bce = max(x,0) - x*t + log1p(exp(-|x|)); out = sum(bce*m)/max(sum(m),1)
// Memory-bound streaming reduction over 3 x 64 MiB fp32/int32 arrays.

__global__ __launch_bounds__(256) void bce_masked_sum_kernel(
    const float4* __restrict__ logits,
    const float4* __restrict__ targets,
    const int4*   __restrict__ mask,
    double* __restrict__ ws,   // ws[0] = sum, ws[1] = count
    int n4)
{
    int tid    = blockIdx.x * blockDim.x + threadIdx.x;
    int stride = gridDim.x * blockDim.x;

    float sum = 0.0f;
    float cnt = 0.0f;

    for (int i = tid; i < n4; i += stride) {
        float4 x = logits[i];
        float4 t = targets[i];
        int4   m = mask[i];

        float xs[4] = {x.x, x.y, x.z, x.w};
        float ts[4] = {t.x, t.y, t.z, t.w};
        int   ms[4] = {m.x, m.y, m.z, m.w};

        #pragma unroll
        for (int k = 0; k < 4; ++k) {
            float xv  = xs[k];
            float bce = fmaxf(xv, 0.0f) - xv * ts[k] + log1pf(__expf(-fabsf(xv)));
            if (ms[k]) {
                sum += bce;
                cnt += 1.0f;
            }
        }
    }

    // Wave-64 shuffle reduction
    #pragma unroll
    for (int off = 32; off > 0; off >>= 1) {
        sum += __shfl_down(sum, off, 64);
        cnt += __shfl_down(cnt, off, 64);
    }

    // One atomic per wave (lane 0)
    if ((threadIdx.x & 63) == 0) {
        atomicAdd(&ws[0], (double)sum);
        atomicAdd(&ws[1], (double)cnt);
    }
}

__global__ void bce_finalize_kernel(const double* __restrict__ ws,
                                    float* __restrict__ out)
{
    double total = ws[0];
    double count = ws[1];
    out[0] = (float)(total / fmax(count, 1.0));
}

extern "C" void kernel_launch(void* const* d_in, const int* in_sizes, int n_in,
                              void* d_out, int out_size, void* d_ws, size_t ws_size,
                              hipStream_t stream) {
    const float4* logits = (const float4*)d_in[0];
    const float4* targets = (const float4*)d_in[1];
    const int4*   mask    = (const int4*)d_in[2];
    float* out = (float*)d_out;
    double* ws = (double*)d_ws;

    int n  = in_sizes[0];      // 16*1024*1024, divisible by 4
    int n4 = n / 4;

    // ws is poisoned with 0xAA before every timed launch — zero the accumulators.
    hipMemsetAsync(ws, 0, 2 * sizeof(double), stream);

    const int block = 256;
    const int grid  = 4096;    // grid-stride: ~4 float4 iters/thread
    bce_masked_sum_kernel<<<grid, block, 0, stream>>>(logits, targets, mask, ws, n4);
    bce_finalize_kernel<<<1, 1, 0, stream>>>(ws, out);
}

// Round 2
// 201.145 us; speedup vs baseline: 2.7092x; 2.7092x over previous
//
#include <hip/hip_runtime.h>
#include <math.h>

// Masked-mean BCE-with-logits:
//   bce = max(x,0) - x*t + log1p(exp(-|x|)); out = sum(bce*m)/max(sum(m),1)
// Memory-bound streaming reduction over 3 x 64 MiB fp32/int32 arrays.
//
// R1 lesson: 32K same-address double atomics serialized at ~30cy each = 419us.
// Now: per-block partial (float2) written to ws, second kernel reduces.

__global__ __launch_bounds__(256) void bce_masked_partial_kernel(
    const float4* __restrict__ logits,
    const float4* __restrict__ targets,
    const int4*   __restrict__ mask,
    float2* __restrict__ partials,   // one float2 {sum, count} per block
    int n4)
{
    int tid    = blockIdx.x * blockDim.x + threadIdx.x;
    int stride = gridDim.x * blockDim.x;

    float sum = 0.0f;
    float cnt = 0.0f;

    for (int i = tid; i < n4; i += stride) {
        float4 x = logits[i];
        float4 t = targets[i];
        int4   m = mask[i];

        float xs[4] = {x.x, x.y, x.z, x.w};
        float ts[4] = {t.x, t.y, t.z, t.w};
        int   ms[4] = {m.x, m.y, m.z, m.w};

        #pragma unroll
        for (int k = 0; k < 4; ++k) {
            float xv  = xs[k];
            float bce = fmaxf(xv, 0.0f) - xv * ts[k] + log1pf(__expf(-fabsf(xv)));
            if (ms[k]) {
                sum += bce;
                cnt += 1.0f;
            }
        }
    }

    // Wave-64 shuffle reduction
    #pragma unroll
    for (int off = 32; off > 0; off >>= 1) {
        sum += __shfl_down(sum, off, 64);
        cnt += __shfl_down(cnt, off, 64);
    }

    // Cross-wave reduction via LDS (4 waves per 256-thread block)
    __shared__ float2 wsum[4];
    int lane = threadIdx.x & 63;
    int wid  = threadIdx.x >> 6;
    if (lane == 0) wsum[wid] = make_float2(sum, cnt);
    __syncthreads();
    if (threadIdx.x == 0) {
        float s = 0.0f, c = 0.0f;
        #pragma unroll
        for (int w = 0; w < 4; ++w) { s += wsum[w].x; c += wsum[w].y; }
        partials[blockIdx.x] = make_float2(s, c);
    }
}

__global__ __launch_bounds__(256) void bce_finalize_kernel(
    const float2* __restrict__ partials,
    float* __restrict__ out,
    int nblocks)
{
    float sum = 0.0f, cnt = 0.0f;
    for (int i = threadIdx.x; i < nblocks; i += 256) {
        float2 p = partials[i];
        sum += p.x;
        cnt += p.y;
    }
    #pragma unroll
    for (int off = 32; off > 0; off >>= 1) {
        sum += __shfl_down(sum, off, 64);
        cnt += __shfl_down(cnt, off, 64);
    }
    __shared__ float2 wsum[4];
    int lane = threadIdx.x & 63;
    int wid  = threadIdx.x >> 6;
    if (lane == 0) wsum[wid] = make_float2(sum, cnt);
    __syncthreads();
    if (threadIdx.x == 0) {
        float s = 0.0f, c = 0.0f;
        #pragma unroll
        for (int w = 0; w < 4; ++w) { s += wsum[w].x; c += wsum[w].y; }
        out[0] = s / fmaxf(c, 1.0f);
    }
}

extern "C" void kernel_launch(void* const* d_in, const int* in_sizes, int n_in,
                              void* d_out, int out_size, void* d_ws, size_t ws_size,
                              hipStream_t stream) {
    const float4* logits  = (const float4*)d_in[0];
    const float4* targets = (const float4*)d_in[1];
    const int4*   mask    = (const int4*)d_in[2];
    float*  out      = (float*)d_out;
    float2* partials = (float2*)d_ws;

    int n  = in_sizes[0];      // 16*1024*1024, divisible by 4
    int n4 = n / 4;

    // 1024 blocks x 256 threads: 16 float4 iters/thread, 16 waves/CU.
    int grid = 1024;
    // Safety: partials must fit in ws (8 B per block).
    size_t need = (size_t)grid * sizeof(float2);
    if (ws_size < need) {
        grid = (int)(ws_size / sizeof(float2));
        if (grid < 1) grid = 1;
    }

    bce_masked_partial_kernel<<<grid, 256, 0, stream>>>(logits, targets, mask, partials, n4);
    bce_finalize_kernel<<<1, 256, 0, stream>>>(partials, out, grid);
}

// Round 3
// 196.197 us; speedup vs baseline: 2.7776x; 1.0252x over previous
//
#include <hip/hip_runtime.h>
#include <math.h>

// Masked-mean BCE-with-logits:
//   bce = max(x,0) - x*t + log1p(exp(-|x|)); out = sum(bce*m)/max(sum(m),1)
//
// R1 lesson: same-address double atomics serialize (~30cy each) -> two-stage
//            block-partial reduction instead.
// R2 lesson: libm log1pf is ~250 VALU inst/elem -> VALU-bound at 65% busy.
//            Use HW transcendentals: softplus(-|x|) = __logf(1+__expf(-|x|)),
//            ~6 VALU ops. Error << 1.6e-2 threshold on the mean.

__global__ __launch_bounds__(256) void bce_masked_partial_kernel(
    const float4* __restrict__ logits,
    const float4* __restrict__ targets,
    const int4*   __restrict__ mask,
    float2* __restrict__ partials,   // one float2 {sum, count} per block
    int n4)
{
    int tid    = blockIdx.x * blockDim.x + threadIdx.x;
    int stride = gridDim.x * blockDim.x;

    float sum = 0.0f;
    float cnt = 0.0f;

    for (int i = tid; i < n4; i += stride) {
        float4 x = logits[i];
        float4 t = targets[i];
        int4   m = mask[i];

        float xs[4] = {x.x, x.y, x.z, x.w};
        float ts[4] = {t.x, t.y, t.z, t.w};
        int   ms[4] = {m.x, m.y, m.z, m.w};

        #pragma unroll
        for (int k = 0; k < 4; ++k) {
            float xv = xs[k];
            // softplus(-|x|) via HW v_exp_f32 / v_log_f32
            float sp  = __logf(1.0f + __expf(-fabsf(xv)));
            float bce = fmaxf(xv, 0.0f) - xv * ts[k] + sp;
            float mf  = (float)ms[k];   // mask is 0/1
            sum += bce * mf;
            cnt += mf;
        }
    }

    // Wave-64 shuffle reduction
    #pragma unroll
    for (int off = 32; off > 0; off >>= 1) {
        sum += __shfl_down(sum, off, 64);
        cnt += __shfl_down(cnt, off, 64);
    }

    // Cross-wave reduction via LDS (4 waves per 256-thread block)
    __shared__ float2 wsum[4];
    int lane = threadIdx.x & 63;
    int wid  = threadIdx.x >> 6;
    if (lane == 0) wsum[wid] = make_float2(sum, cnt);
    __syncthreads();
    if (threadIdx.x == 0) {
        float s = 0.0f, c = 0.0f;
        #pragma unroll
        for (int w = 0; w < 4; ++w) { s += wsum[w].x; c += wsum[w].y; }
        partials[blockIdx.x] = make_float2(s, c);
    }
}

__global__ __launch_bounds__(256) void bce_finalize_kernel(
    const float2* __restrict__ partials,
    float* __restrict__ out,
    int nblocks)
{
    float sum = 0.0f, cnt = 0.0f;
    for (int i = threadIdx.x; i < nblocks; i += 256) {
        float2 p = partials[i];
        sum += p.x;
        cnt += p.y;
    }
    #pragma unroll
    for (int off = 32; off > 0; off >>= 1) {
        sum += __shfl_down(sum, off, 64);
        cnt += __shfl_down(cnt, off, 64);
    }
    __shared__ float2 wsum[4];
    int lane = threadIdx.x & 63;
    int wid  = threadIdx.x >> 6;
    if (lane == 0) wsum[wid] = make_float2(sum, cnt);
    __syncthreads();
    if (threadIdx.x == 0) {
        float s = 0.0f, c = 0.0f;
        #pragma unroll
        for (int w = 0; w < 4; ++w) { s += wsum[w].x; c += wsum[w].y; }
        out[0] = s / fmaxf(c, 1.0f);
    }
}

extern "C" void kernel_launch(void* const* d_in, const int* in_sizes, int n_in,
                              void* d_out, int out_size, void* d_ws, size_t ws_size,
                              hipStream_t stream) {
    const float4* logits  = (const float4*)d_in[0];
    const float4* targets = (const float4*)d_in[1];
    const int4*   mask    = (const int4*)d_in[2];
    float*  out      = (float*)d_out;
    float2* partials = (float2*)d_ws;

    int n  = in_sizes[0];      // 16*1024*1024, divisible by 4
    int n4 = n / 4;

    // 2048 blocks x 256 threads = 32 waves/CU resident; 8 float4 iters/thread.
    int grid = 2048;
    size_t need = (size_t)grid * sizeof(float2);
    if (ws_size < need) {
        grid = (int)(ws_size / sizeof(float2));
        if (grid < 1) grid = 1;
    }

    bce_masked_partial_kernel<<<grid, 256, 0, stream>>>(logits, targets, mask, partials, n4);
    bce_finalize_kernel<<<1, 256, 0, stream>>>(partials, out, grid);
}